// Round 7
// baseline (396.706 us; speedup 1.0000x reference)
//
#include <hip/hip_runtime.h>

#define B_ 64
#define N_ 256
#define V_ 2048
#define E_ 1024
#define MROWS 16384  // B_*N_

typedef __bf16 bf16_t;
typedef bf16_t bf16x8 __attribute__((ext_vector_type(8)));
typedef float f32x4 __attribute__((ext_vector_type(4)));

// ws layout (float units):
#define OFF_S   0         // s      [16384]
#define OFF_LR  16384     // LR     [16384*128]
#define OFF_FT  2113536   // featsT [2048*64]
#define OFF_WB  2244608   // Wb bf16[128*2048] (= 131072 floats)

// ---------------- kernel 1: weight-norm scale folded into bf16 weights ----
// also zeroes featsT (removes a separate memset dispatch)
__global__ void kprep(const float* __restrict__ U1v, const float* __restrict__ U1g,
                      const float* __restrict__ U2v, const float* __restrict__ U2g,
                      bf16_t* __restrict__ Wb, float* __restrict__ featsT) {
    {
        float4 z = {0.f, 0.f, 0.f, 0.f};
        *(float4*)&featsT[(size_t)(blockIdx.x * 256 + threadIdx.x) * 4] = z;
    }
    __shared__ float red[256];
    __shared__ float sc;
    const int r = blockIdx.x;  // 0..127
    const float* v = (r < 64) ? (U1v + (size_t)r * V_) : (U2v + (size_t)(r - 64) * V_);
    float ss = 0.f;
    for (int i = threadIdx.x; i < V_; i += 256) { float x = v[i]; ss += x * x; }
    red[threadIdx.x] = ss;
    __syncthreads();
    for (int o = 128; o > 0; o >>= 1) {
        if (threadIdx.x < (unsigned)o) red[threadIdx.x] += red[threadIdx.x + o];
        __syncthreads();
    }
    if (threadIdx.x == 0) {
        float g = (r < 64) ? U1g[r] : U2g[r - 64];
        sc = g * rsqrtf(red[0]);
    }
    __syncthreads();
    const float s = sc;
    const int k = threadIdx.x * 8;
    float4 f0 = *(const float4*)(v + k);
    float4 f1 = *(const float4*)(v + k + 4);
    bf16x8 o;
    o[0] = (bf16_t)(f0.x * s); o[1] = (bf16_t)(f0.y * s);
    o[2] = (bf16_t)(f0.z * s); o[3] = (bf16_t)(f0.w * s);
    o[4] = (bf16_t)(f1.x * s); o[5] = (bf16_t)(f1.y * s);
    o[6] = (bf16_t)(f1.z * s); o[7] = (bf16_t)(f1.w * s);
    *(bf16x8*)(Wb + (size_t)r * V_ + k) = o;
}

// ---------------- kernel 2: MFMA bf16 projections, distance-2 prefetch ----
// LR[16384x128] = relu(Vmat * Wb^T + bias). Tile 32m x 128n, BK=64, grid 512.
// All global loads (A fp32 + B bf16) are register-prefetched 2 iterations
// ahead (~550+ cyc cover); LDS single-buffered, 2 barriers/iter (R3 proven
// semantics, no DMA, no dbuf race). XOR-swizzled chunks: effective
// conflict-free (8 lanes/4-bank group = 8-phase minimum for 1KB wave access).
#define BK 64
__global__ __launch_bounds__(256) void gemm_lr(
    const float* __restrict__ V, const bf16_t* __restrict__ Wb,
    const float* __restrict__ U1b, const float* __restrict__ U2b,
    float* __restrict__ LR) {
    __shared__ bf16_t As[32 * BK];    // 4 KB
    __shared__ bf16_t Bs[128 * BK];   // 16 KB
    const int t = threadIdx.x;
    const int m0 = blockIdx.x * 32;
    const int wv = t >> 6, lane = t & 63;
    const int lm = lane & 15, lq = lane >> 4;
    const int n0w = wv * 32;

    // A staging: thread -> (row ar 0..31, chunk au 0..7), 8 floats each
    const int ar = t >> 3, au = t & 7;
    const float* aptr = V + (size_t)(m0 + ar) * V_ + au * 8;
    bf16_t* adst = &As[ar * BK + ((au ^ (ar & 7)) * 8)];

    // B staging: thread -> (row br 0..127, half bh 0/1), 32 elems (64 B) each
    const int br = t >> 1, bh = t & 1;
    const bf16_t* bptr = Wb + (size_t)br * V_ + bh * 32;
    bf16_t* bdst = &Bs[br * BK];
    const int bperm0 = (bh * 4 + 0) ^ (br & 7);
    const int bperm1 = (bh * 4 + 1) ^ (br & 7);
    const int bperm2 = (bh * 4 + 2) ^ (br & 7);
    const int bperm3 = (bh * 4 + 3) ^ (br & 7);

    f32x4 acc[2][2];
#pragma unroll
    for (int i = 0; i < 2; ++i)
#pragma unroll
        for (int j = 0; j < 2; ++j) acc[i][j] = (f32x4){0.f, 0.f, 0.f, 0.f};

    // prologue: load stage 0 (k=0) and stage 1 (k=64) into registers
    float4 a0s[2], a1s[2];
    uint4  bbs[2][4];
#pragma unroll
    for (int p = 0; p < 2; ++p) {
        a0s[p] = *(const float4*)(aptr + p * 64);
        a1s[p] = *(const float4*)(aptr + p * 64 + 4);
#pragma unroll
        for (int c = 0; c < 4; ++c)
            bbs[p][c] = *(const uint4*)(bptr + p * 64 + c * 8);
    }

    for (int k0 = 0; k0 < V_; k0 += 128) {
#pragma unroll
        for (int pp = 0; pp < 2; ++pp) {
            const int kc = k0 + pp * 64;
            // LDS write from stage pp
            {
                bf16x8 av;
                av[0] = (bf16_t)a0s[pp].x; av[1] = (bf16_t)a0s[pp].y;
                av[2] = (bf16_t)a0s[pp].z; av[3] = (bf16_t)a0s[pp].w;
                av[4] = (bf16_t)a1s[pp].x; av[5] = (bf16_t)a1s[pp].y;
                av[6] = (bf16_t)a1s[pp].z; av[7] = (bf16_t)a1s[pp].w;
                *(bf16x8*)adst = av;
                *(uint4*)(bdst + bperm0 * 8) = bbs[pp][0];
                *(uint4*)(bdst + bperm1 * 8) = bbs[pp][1];
                *(uint4*)(bdst + bperm2 * 8) = bbs[pp][2];
                *(uint4*)(bdst + bperm3 * 8) = bbs[pp][3];
            }
            // refill stage pp from kc+128 (consumed 2 bodies later)
            if (kc + 128 < V_) {
                a0s[pp] = *(const float4*)(aptr + kc + 128);
                a1s[pp] = *(const float4*)(aptr + kc + 128 + 4);
#pragma unroll
                for (int c = 0; c < 4; ++c)
                    bbs[pp][c] = *(const uint4*)(bptr + kc + 128 + c * 8);
            }
            __syncthreads();  // LDS writes visible

            bf16x8 af[2][2], bfr[2][2];
#pragma unroll
            for (int i = 0; i < 2; ++i)
#pragma unroll
                for (int kf = 0; kf < 2; ++kf)
                    af[i][kf] = *(bf16x8*)&As[(i * 16 + lm) * BK + (((kf * 4 + lq) ^ (lm & 7)) * 8)];
#pragma unroll
            for (int j = 0; j < 2; ++j)
#pragma unroll
                for (int kf = 0; kf < 2; ++kf)
                    bfr[j][kf] = *(bf16x8*)&Bs[(n0w + j * 16 + lm) * BK + (((kf * 4 + lq) ^ (lm & 7)) * 8)];
#pragma unroll
            for (int i = 0; i < 2; ++i)
#pragma unroll
                for (int j = 0; j < 2; ++j) {
                    acc[i][j] = __builtin_amdgcn_mfma_f32_16x16x32_bf16(af[i][0], bfr[j][0], acc[i][j], 0, 0, 0);
                    acc[i][j] = __builtin_amdgcn_mfma_f32_16x16x32_bf16(af[i][1], bfr[j][1], acc[i][j], 0, 0, 0);
                }
            __syncthreads();  // done reading As/Bs
        }
    }
    // epilogue: bias + relu. C/D: n = lane&15 (+16j), m = lq*4 + reg (+16i)
#pragma unroll
    for (int j = 0; j < 2; ++j) {
        const int n = n0w + j * 16 + lm;
        const float bi = (n < 64) ? U1b[n] : U2b[n - 64];
#pragma unroll
        for (int i = 0; i < 2; ++i)
#pragma unroll
            for (int r = 0; r < 4; ++r) {
                const int m = m0 + i * 16 + lq * 4 + r;
                LR[(size_t)m * 128 + n] = fmaxf(acc[i][j][r] + bi, 0.f);
            }
    }
}

// ---------------- kernel 3: fused d + Lbar + s (per batch) ----------------
__global__ __launch_bounds__(256) void kds(const float* __restrict__ LR, float* __restrict__ s) {
    __shared__ float dl[256];
    __shared__ float red[4][64];
    __shared__ float lbar[64];
    const int b = blockIdx.x, t = threadIdx.x;
    const float* Lb = LR + (size_t)b * N_ * 128;
    const float* row = Lb + (size_t)t * 128;
    float dd = 0.f;
#pragma unroll
    for (int k = 0; k < 64; k += 4) {
        float4 l = *(const float4*)(row + k);
        float4 r = *(const float4*)(row + 64 + k);
        dd += l.x * r.x + l.y * r.y + l.z * r.z + l.w * r.w;
    }
    const float dv = rsqrtf(dd + 1e-6f);
    dl[t] = dv;
    __syncthreads();
    const int k = t & 63, g = t >> 6;
    float acc = 0.f;
    for (int n = g; n < N_; n += 4)
        acc += dl[n] * Lb[(size_t)n * 128 + 64 + k];
    red[g][k] = acc;
    __syncthreads();
    if (t < 64) lbar[t] = red[0][t] + red[1][t] + red[2][t] + red[3][t];
    __syncthreads();
    float a2 = 0.f;
#pragma unroll 8
    for (int kk = 0; kk < 64; ++kk) a2 += lbar[kk] * row[kk];
    s[b * N_ + t] = ((float)(N_ + 1) - dv * a2) * (1.0f / (float)N_);
}

// ---------------- kernel 4: featsT[v][b] += partial over m-chunk ----------
__global__ __launch_bounds__(256) void kfeats(const float* __restrict__ Vmat,
                                              const float* __restrict__ s,
                                              float* __restrict__ featsT) {
    const int b = blockIdx.x >> 3, vc = (blockIdx.x >> 2) & 1, mc = blockIdx.x & 3;
    __shared__ float sl[64];
    const int t = threadIdx.x;
    if (t < 64) sl[t] = s[b * N_ + mc * 64 + t];
    __syncthreads();
    const int v = vc * 1024 + t * 4;
    const float* base = Vmat + (size_t)b * N_ * V_ + (size_t)mc * 64 * V_ + v;
    float4 a = {0.f, 0.f, 0.f, 0.f};
    for (int m = 0; m < 64; m += 8) {
        float4 x[8];
#pragma unroll
        for (int u = 0; u < 8; ++u) x[u] = *(const float4*)(base + (size_t)(m + u) * V_);
#pragma unroll
        for (int u = 0; u < 8; ++u) {
            float sv = sl[m + u];
            a.x += sv * x[u].x; a.y += sv * x[u].y;
            a.z += sv * x[u].z; a.w += sv * x[u].w;
        }
    }
    atomicAdd(&featsT[(size_t)(v + 0) * 64 + b], a.x);
    atomicAdd(&featsT[(size_t)(v + 1) * 64 + b], a.y);
    atomicAdd(&featsT[(size_t)(v + 2) * 64 + b], a.z);
    atomicAdd(&featsT[(size_t)(v + 3) * 64 + b], a.w);
}

// ---------------- kernel 5: fused linear + BatchNorm ----------------------
// (b_lin dropped: constant per-column shift cancels in BatchNorm)
__global__ __launch_bounds__(256) void klinbn(const float* __restrict__ featsT,
                                              const float* __restrict__ Wl,
                                              const float* __restrict__ gamma,
                                              const float* __restrict__ beta,
                                              float* __restrict__ out) {
    __shared__ float red[4][4][64];
    const int e0 = blockIdx.x * 4;
    const int t = threadIdx.x, b = t & 63, g = t >> 6;
    const float* w0 = Wl + (size_t)(e0 + 0) * V_ + g * 512;
    const float* w1 = Wl + (size_t)(e0 + 1) * V_ + g * 512;
    const float* w2 = Wl + (size_t)(e0 + 2) * V_ + g * 512;
    const float* w3 = Wl + (size_t)(e0 + 3) * V_ + g * 512;
    const float* f = featsT + (size_t)g * 512 * 64 + b;
    float a0 = 0.f, a1 = 0.f, a2 = 0.f, a3 = 0.f;
#pragma unroll 4
    for (int k = 0; k < 512; ++k) {
        float fv = f[(size_t)k * 64];
        a0 += fv * w0[k]; a1 += fv * w1[k]; a2 += fv * w2[k]; a3 += fv * w3[k];
    }
    red[g][0][b] = a0; red[g][1][b] = a1; red[g][2][b] = a2; red[g][3][b] = a3;
    __syncthreads();
    const int e = t >> 6;  // wave e owns e-row e0+e across lanes b
    float v = red[0][e][b] + red[1][e][b] + red[2][e][b] + red[3][e][b];
    float sum = v;
#pragma unroll
    for (int o = 1; o < 64; o <<= 1) sum += __shfl_xor(sum, o, 64);
    float mu = sum * (1.f / 64.f);
    float dvv = v - mu;
    float q = dvv * dvv;
#pragma unroll
    for (int o = 1; o < 64; o <<= 1) q += __shfl_xor(q, o, 64);
    float inv = rsqrtf(q * (1.f / 64.f) + 1e-5f);
    float res = gamma[e0 + e] * dvv * inv + beta[e0 + e];
    __syncthreads();
    red[0][e][b] = res;
    __syncthreads();
    const int b2 = t >> 2, j = t & 3;
    out[(size_t)b2 * E_ + e0 + j] = red[0][j][b2];
}

extern "C" void kernel_launch(void* const* d_in, const int* in_sizes, int n_in,
                              void* d_out, int out_size, void* d_ws, size_t ws_size,
                              hipStream_t stream) {
    const float* Vmat = (const float*)d_in[0];
    const float* U1v  = (const float*)d_in[1];
    const float* U1g  = (const float*)d_in[2];
    const float* U1b  = (const float*)d_in[3];
    const float* U2v  = (const float*)d_in[4];
    const float* U2g  = (const float*)d_in[5];
    const float* U2b  = (const float*)d_in[6];
    const float* Wl   = (const float*)d_in[7];
    // d_in[8] = b_lin: unused (cancels in BatchNorm)
    const float* gam  = (const float*)d_in[9];
    const float* bet  = (const float*)d_in[10];

    float*  ws     = (float*)d_ws;
    float*  s      = ws + OFF_S;
    float*  LR     = ws + OFF_LR;
    float*  featsT = ws + OFF_FT;
    bf16_t* Wb     = (bf16_t*)(ws + OFF_WB);

    kprep  <<<128, 256, 0, stream>>>(U1v, U1g, U2v, U2g, Wb, featsT);
    gemm_lr<<<MROWS / 32, 256, 0, stream>>>(Vmat, Wb, U1b, U2b, LR);
    kds    <<<B_, 256, 0, stream>>>(LR, s);
    kfeats <<<B_ * 8, 256, 0, stream>>>(Vmat, s, featsT);
    klinbn <<<E_ / 4, 256, 0, stream>>>(featsT, Wl, gam, bet, (float*)d_out);
}

// Round 8
// 305.090 us; speedup vs baseline: 1.3003x; 1.3003x over previous
//
#include <hip/hip_runtime.h>

#define B_ 64
#define N_ 256
#define V_ 2048
#define E_ 1024
#define MROWS 16384  // B_*N_

typedef __bf16 bf16_t;
typedef bf16_t bf16x8 __attribute__((ext_vector_type(8)));
typedef float f32x4 __attribute__((ext_vector_type(4)));

// ws layout (float units):
#define OFF_S   0         // s      [16384]
#define OFF_LR  16384     // LR     [16384*128]
#define OFF_FT  2113536   // featsT [2048*64]
#define OFF_WB  2244608   // Wb bf16[128*2048] (= 131072 floats)

__device__ __forceinline__ void gload_lds16(const bf16_t* g, bf16_t* l) {
    __builtin_amdgcn_global_load_lds((const __attribute__((address_space(1))) void*)g,
                                     (__attribute__((address_space(3))) void*)l, 16, 0, 0);
}

// ---------------- kernel 1: weight-norm scale folded into bf16 weights ----
// also zeroes featsT (removes a separate memset dispatch)
__global__ void kprep(const float* __restrict__ U1v, const float* __restrict__ U1g,
                      const float* __restrict__ U2v, const float* __restrict__ U2g,
                      bf16_t* __restrict__ Wb, float* __restrict__ featsT) {
    {
        float4 z = {0.f, 0.f, 0.f, 0.f};
        *(float4*)&featsT[(size_t)(blockIdx.x * 256 + threadIdx.x) * 4] = z;
    }
    __shared__ float red[256];
    __shared__ float sc;
    const int r = blockIdx.x;  // 0..127
    const float* v = (r < 64) ? (U1v + (size_t)r * V_) : (U2v + (size_t)(r - 64) * V_);
    float ss = 0.f;
    for (int i = threadIdx.x; i < V_; i += 256) { float x = v[i]; ss += x * x; }
    red[threadIdx.x] = ss;
    __syncthreads();
    for (int o = 128; o > 0; o >>= 1) {
        if (threadIdx.x < (unsigned)o) red[threadIdx.x] += red[threadIdx.x + o];
        __syncthreads();
    }
    if (threadIdx.x == 0) {
        float g = (r < 64) ? U1g[r] : U2g[r - 64];
        sc = g * rsqrtf(red[0]);
    }
    __syncthreads();
    const float s = sc;
    const int k = threadIdx.x * 8;
    float4 f0 = *(const float4*)(v + k);
    float4 f1 = *(const float4*)(v + k + 4);
    bf16x8 o;
    o[0] = (bf16_t)(f0.x * s); o[1] = (bf16_t)(f0.y * s);
    o[2] = (bf16_t)(f0.z * s); o[3] = (bf16_t)(f0.w * s);
    o[4] = (bf16_t)(f1.x * s); o[5] = (bf16_t)(f1.y * s);
    o[6] = (bf16_t)(f1.z * s); o[7] = (bf16_t)(f1.w * s);
    *(bf16x8*)(Wb + (size_t)r * V_ + k) = o;
}

// ---------------- kernel 2: MFMA bf16 projections (R3 proven form) --------
// LR[16384x128] = relu(Vmat * Wb^T + bias). Tile 32m x 128n, BK=64, grid 512.
// B staged via global_load_lds dwordx4 (distance 1), A reg-prefetch+convert,
// XOR-swizzled LDS (conflict-free), single buffer, 2 barriers/iter.
// NOTE: distance-2 register prefetch (R7) spills to scratch — do not retry.
#define BK 64
__global__ __launch_bounds__(256) void gemm_lr(
    const float* __restrict__ V, const bf16_t* __restrict__ Wb,
    const float* __restrict__ U1b, const float* __restrict__ U2b,
    float* __restrict__ LR) {
    __shared__ bf16_t As[32 * BK];
    __shared__ bf16_t Bs[128 * BK];
    const int t = threadIdx.x;
    const int m0 = blockIdx.x * 32;
    const int wv = t >> 6, lane = t & 63;
    const int lm = lane & 15, lq = lane >> 4;
    const int n0w = wv * 32;

    // A staging: thread -> (row 0..31, 8-elem chunk au 0..7), XOR swizzle
    const int arow = t >> 3, au = t & 7;
    const float* aptr = V + (size_t)(m0 + arow) * V_ + au * 8;
    bf16_t* adst = &As[arow * BK + ((au ^ (arow & 7)) * 8)];

    // B DMA: lane -> (row = q*32 + wv*8 + rloc, swizzled chunk uu)
    const int rloc = lane >> 3;
    const int uu = (lane & 7) ^ rloc;
    const bf16_t* bgbase = Wb + (size_t)(wv * 8 + rloc) * V_ + uu * 8;

    f32x4 acc[2][2];
#pragma unroll
    for (int i = 0; i < 2; ++i)
#pragma unroll
        for (int j = 0; j < 2; ++j) acc[i][j] = (f32x4){0.f, 0.f, 0.f, 0.f};

    // prologue: B DMA for k0=0, A regs for k0=0
#pragma unroll
    for (int q = 0; q < 4; ++q)
        gload_lds16(bgbase + (size_t)q * 32 * V_, &Bs[(q * 32 + wv * 8) * BK]);
    float4 ap0 = *(const float4*)(aptr);
    float4 ap1 = *(const float4*)(aptr + 4);

    for (int k0 = 0; k0 < V_; k0 += BK) {
        bf16x8 av;
        av[0] = (bf16_t)ap0.x; av[1] = (bf16_t)ap0.y; av[2] = (bf16_t)ap0.z; av[3] = (bf16_t)ap0.w;
        av[4] = (bf16_t)ap1.x; av[5] = (bf16_t)ap1.y; av[6] = (bf16_t)ap1.z; av[7] = (bf16_t)ap1.w;
        *(bf16x8*)adst = av;
        __syncthreads();  // B DMA + A writes visible

        bf16x8 af[2][2], bfr[2][2];
#pragma unroll
        for (int i = 0; i < 2; ++i)
#pragma unroll
            for (int kf = 0; kf < 2; ++kf)
                af[i][kf] = *(bf16x8*)&As[(i * 16 + lm) * BK + (((kf * 4 + lq) ^ (lm & 7)) * 8)];
#pragma unroll
        for (int j = 0; j < 2; ++j)
#pragma unroll
            for (int kf = 0; kf < 2; ++kf)
                bfr[j][kf] = *(bf16x8*)&Bs[(n0w + j * 16 + lm) * BK + (((kf * 4 + lq) ^ (lm & 7)) * 8)];

        if (k0 + BK < V_) {  // A reg prefetch for next iter
            ap0 = *(const float4*)(aptr + k0 + BK);
            ap1 = *(const float4*)(aptr + k0 + BK + 4);
        }
#pragma unroll
        for (int i = 0; i < 2; ++i)
#pragma unroll
            for (int j = 0; j < 2; ++j) {
                acc[i][j] = __builtin_amdgcn_mfma_f32_16x16x32_bf16(af[i][0], bfr[j][0], acc[i][j], 0, 0, 0);
                acc[i][j] = __builtin_amdgcn_mfma_f32_16x16x32_bf16(af[i][1], bfr[j][1], acc[i][j], 0, 0, 0);
            }
        __syncthreads();  // done reading As/Bs
        if (k0 + BK < V_) {
#pragma unroll
            for (int q = 0; q < 4; ++q)
                gload_lds16(bgbase + (size_t)q * 32 * V_ + (k0 + BK), &Bs[(q * 32 + wv * 8) * BK]);
        }
    }
    // epilogue: bias + relu. C/D: n = lane&15 (+16j), m = lq*4 + reg (+16i)
#pragma unroll
    for (int j = 0; j < 2; ++j) {
        const int n = n0w + j * 16 + lm;
        const float bi = (n < 64) ? U1b[n] : U2b[n - 64];
#pragma unroll
        for (int i = 0; i < 2; ++i)
#pragma unroll
            for (int r = 0; r < 4; ++r) {
                const int m = m0 + i * 16 + lq * 4 + r;
                LR[(size_t)m * 128 + n] = fmaxf(acc[i][j][r] + bi, 0.f);
            }
    }
}

// ---------------- kernel 3: fused d + Lbar + s (per batch) ----------------
__global__ __launch_bounds__(256) void kds(const float* __restrict__ LR, float* __restrict__ s) {
    __shared__ float dl[256];
    __shared__ float red[4][64];
    __shared__ float lbar[64];
    const int b = blockIdx.x, t = threadIdx.x;
    const float* Lb = LR + (size_t)b * N_ * 128;
    const float* row = Lb + (size_t)t * 128;
    float dd = 0.f;
#pragma unroll
    for (int k = 0; k < 64; k += 4) {
        float4 l = *(const float4*)(row + k);
        float4 r = *(const float4*)(row + 64 + k);
        dd += l.x * r.x + l.y * r.y + l.z * r.z + l.w * r.w;
    }
    const float dv = rsqrtf(dd + 1e-6f);
    dl[t] = dv;
    __syncthreads();
    const int k = t & 63, g = t >> 6;
    float acc = 0.f;
    for (int n = g; n < N_; n += 4)
        acc += dl[n] * Lb[(size_t)n * 128 + 64 + k];
    red[g][k] = acc;
    __syncthreads();
    if (t < 64) lbar[t] = red[0][t] + red[1][t] + red[2][t] + red[3][t];
    __syncthreads();
    float a2 = 0.f;
#pragma unroll 8
    for (int kk = 0; kk < 64; ++kk) a2 += lbar[kk] * row[kk];
    s[b * N_ + t] = ((float)(N_ + 1) - dv * a2) * (1.0f / (float)N_);
}

// ---------------- kernel 4: featsT[v][b] += partial over m-chunk ----------
__global__ __launch_bounds__(256) void kfeats(const float* __restrict__ Vmat,
                                              const float* __restrict__ s,
                                              float* __restrict__ featsT) {
    const int b = blockIdx.x >> 3, vc = (blockIdx.x >> 2) & 1, mc = blockIdx.x & 3;
    __shared__ float sl[64];
    const int t = threadIdx.x;
    if (t < 64) sl[t] = s[b * N_ + mc * 64 + t];
    __syncthreads();
    const int v = vc * 1024 + t * 4;
    const float* base = Vmat + (size_t)b * N_ * V_ + (size_t)mc * 64 * V_ + v;
    float4 a = {0.f, 0.f, 0.f, 0.f};
    for (int m = 0; m < 64; m += 8) {
        float4 x[8];
#pragma unroll
        for (int u = 0; u < 8; ++u) x[u] = *(const float4*)(base + (size_t)(m + u) * V_);
#pragma unroll
        for (int u = 0; u < 8; ++u) {
            float sv = sl[m + u];
            a.x += sv * x[u].x; a.y += sv * x[u].y;
            a.z += sv * x[u].z; a.w += sv * x[u].w;
        }
    }
    atomicAdd(&featsT[(size_t)(v + 0) * 64 + b], a.x);
    atomicAdd(&featsT[(size_t)(v + 1) * 64 + b], a.y);
    atomicAdd(&featsT[(size_t)(v + 2) * 64 + b], a.z);
    atomicAdd(&featsT[(size_t)(v + 3) * 64 + b], a.w);
}

// ---------------- kernel 5: fused linear + BatchNorm (512 thr, 8-way K) ---
// (b_lin dropped: constant per-column shift cancels in BatchNorm)
__global__ __launch_bounds__(512) void klinbn(const float* __restrict__ featsT,
                                              const float* __restrict__ Wl,
                                              const float* __restrict__ gamma,
                                              const float* __restrict__ beta,
                                              float* __restrict__ out) {
    __shared__ float red[8][4][64];
    const int e0 = blockIdx.x * 4;
    const int t = threadIdx.x, b = t & 63, g = t >> 6;  // g: 0..7 k-slices
    const float* w0 = Wl + (size_t)(e0 + 0) * V_ + g * 256;
    const float* w1 = Wl + (size_t)(e0 + 1) * V_ + g * 256;
    const float* w2 = Wl + (size_t)(e0 + 2) * V_ + g * 256;
    const float* w3 = Wl + (size_t)(e0 + 3) * V_ + g * 256;
    const float* f = featsT + (size_t)g * 256 * 64 + b;
    float a0 = 0.f, a1 = 0.f, a2 = 0.f, a3 = 0.f;
#pragma unroll 4
    for (int k = 0; k < 256; ++k) {
        float fv = f[(size_t)k * 64];
        a0 += fv * w0[k]; a1 += fv * w1[k]; a2 += fv * w2[k]; a3 += fv * w3[k];
    }
    red[g][0][b] = a0; red[g][1][b] = a1; red[g][2][b] = a2; red[g][3][b] = a3;
    __syncthreads();
    if (t < 256) {
        const int e = t >> 6;  // wave e owns e-row e0+e across lanes b
        float v = 0.f;
#pragma unroll
        for (int gg = 0; gg < 8; ++gg) v += red[gg][e][b];
        float sum = v;
#pragma unroll
        for (int o = 1; o < 64; o <<= 1) sum += __shfl_xor(sum, o, 64);
        float mu = sum * (1.f / 64.f);
        float dvv = v - mu;
        float q = dvv * dvv;
#pragma unroll
        for (int o = 1; o < 64; o <<= 1) q += __shfl_xor(q, o, 64);
        float inv = rsqrtf(q * (1.f / 64.f) + 1e-5f);
        red[0][e][b] = gamma[e0 + e] * dvv * inv + beta[e0 + e];
    }
    __syncthreads();
    if (t < 256) {
        const int b2 = t >> 2, j = t & 3;
        out[(size_t)b2 * E_ + e0 + j] = red[0][j][b2];
    }
}

extern "C" void kernel_launch(void* const* d_in, const int* in_sizes, int n_in,
                              void* d_out, int out_size, void* d_ws, size_t ws_size,
                              hipStream_t stream) {
    const float* Vmat = (const float*)d_in[0];
    const float* U1v  = (const float*)d_in[1];
    const float* U1g  = (const float*)d_in[2];
    const float* U1b  = (const float*)d_in[3];
    const float* U2v  = (const float*)d_in[4];
    const float* U2g  = (const float*)d_in[5];
    const float* U2b  = (const float*)d_in[6];
    const float* Wl   = (const float*)d_in[7];
    // d_in[8] = b_lin: unused (cancels in BatchNorm)
    const float* gam  = (const float*)d_in[9];
    const float* bet  = (const float*)d_in[10];

    float*  ws     = (float*)d_ws;
    float*  s      = ws + OFF_S;
    float*  LR     = ws + OFF_LR;
    float*  featsT = ws + OFF_FT;
    bf16_t* Wb     = (bf16_t*)(ws + OFF_WB);

    kprep  <<<128, 256, 0, stream>>>(U1v, U1g, U2v, U2g, Wb, featsT);
    gemm_lr<<<MROWS / 32, 256, 0, stream>>>(Vmat, Wb, U1b, U2b, LR);
    kds    <<<B_, 256, 0, stream>>>(LR, s);
    kfeats <<<B_ * 8, 256, 0, stream>>>(Vmat, s, featsT);
    klinbn <<<E_ / 4, 512, 0, stream>>>(featsT, Wl, gam, bet, (float*)d_out);
}

// Round 9
// 300.418 us; speedup vs baseline: 1.3205x; 1.0156x over previous
//
#include <hip/hip_runtime.h>

#define B_ 64
#define N_ 256
#define V_ 2048
#define E_ 1024
#define MROWS 16384  // B_*N_

typedef __bf16 bf16_t;
typedef bf16_t bf16x8 __attribute__((ext_vector_type(8)));
typedef float f32x4 __attribute__((ext_vector_type(4)));

// ws layout (float units):
#define OFF_S   0         // s      [16384]
#define OFF_LR  16384     // LR     [16384*128]
#define OFF_FT  2113536   // featsT [2048*64]
#define OFF_WB  2244608   // Wb bf16[128*2048] (= 131072 floats)

__device__ __forceinline__ void gload_lds16(const bf16_t* g, bf16_t* l) {
    __builtin_amdgcn_global_load_lds((const __attribute__((address_space(1))) void*)g,
                                     (__attribute__((address_space(3))) void*)l, 16, 0, 0);
}

// ---------------- kernel 1: weight-norm scale folded into bf16 weights ----
// also zeroes featsT (removes a separate memset dispatch)
__global__ void kprep(const float* __restrict__ U1v, const float* __restrict__ U1g,
                      const float* __restrict__ U2v, const float* __restrict__ U2g,
                      bf16_t* __restrict__ Wb, float* __restrict__ featsT) {
    {
        float4 z = {0.f, 0.f, 0.f, 0.f};
        *(float4*)&featsT[(size_t)(blockIdx.x * 256 + threadIdx.x) * 4] = z;
    }
    __shared__ float red[256];
    __shared__ float sc;
    const int r = blockIdx.x;  // 0..127
    const float* v = (r < 64) ? (U1v + (size_t)r * V_) : (U2v + (size_t)(r - 64) * V_);
    float ss = 0.f;
    for (int i = threadIdx.x; i < V_; i += 256) { float x = v[i]; ss += x * x; }
    red[threadIdx.x] = ss;
    __syncthreads();
    for (int o = 128; o > 0; o >>= 1) {
        if (threadIdx.x < (unsigned)o) red[threadIdx.x] += red[threadIdx.x + o];
        __syncthreads();
    }
    if (threadIdx.x == 0) {
        float g = (r < 64) ? U1g[r] : U2g[r - 64];
        sc = g * rsqrtf(red[0]);
    }
    __syncthreads();
    const float s = sc;
    const int k = threadIdx.x * 8;
    float4 f0 = *(const float4*)(v + k);
    float4 f1 = *(const float4*)(v + k + 4);
    bf16x8 o;
    o[0] = (bf16_t)(f0.x * s); o[1] = (bf16_t)(f0.y * s);
    o[2] = (bf16_t)(f0.z * s); o[3] = (bf16_t)(f0.w * s);
    o[4] = (bf16_t)(f1.x * s); o[5] = (bf16_t)(f1.y * s);
    o[6] = (bf16_t)(f1.z * s); o[7] = (bf16_t)(f1.w * s);
    *(bf16x8*)(Wb + (size_t)r * V_ + k) = o;
}

// ---------------- kernel 2: MFMA bf16 projections, BK=128 ------------------
// LR[16384x128] = relu(Vmat * Wb^T + bias). Tile 32m x 128n, grid 512.
// R8 skeleton with BK 64->128: halves the barrier count (32 K-iters -> 16,
// i.e. 64 -> 32 vmcnt-drain barriers). LDS 40 KB (still 2 blocks/CU).
// B via global_load_lds dwordx4, wave-uniform dest; global-side XOR swizzle
// mod 16. A fp32 reg-prefetch (distance 1, 16 VGPRs) + in-reg bf16 convert.
// NOTE: distance-2 register prefetch (R7) spills to scratch — do not retry.
#define BK 128
__global__ __launch_bounds__(256) void gemm_lr(
    const float* __restrict__ V, const bf16_t* __restrict__ Wb,
    const float* __restrict__ U1b, const float* __restrict__ U2b,
    float* __restrict__ LR) {
    __shared__ bf16_t As[32 * BK];    // 8 KB
    __shared__ bf16_t Bs[128 * BK];   // 32 KB
    const int t = threadIdx.x;
    const int m0 = blockIdx.x * 32;
    const int wv = t >> 6, lane = t & 63;
    const int lm = lane & 15, lq = lane >> 4;
    const int n0w = wv * 32;

    // A staging: thread -> (row ar 0..31, chunks au and au+8 of 16), XOR mod16
    const int ar = t >> 3, au = t & 7;
    const float* aptr = V + (size_t)(m0 + ar) * V_ + au * 8;  // +64 floats = chunk au+8
    bf16_t* adst0 = &As[ar * BK + ((au ^ (ar & 15)) * 8)];
    bf16_t* adst1 = &As[ar * BK + (((au + 8) ^ (ar & 15)) * 8)];

    // B DMA: instr covers 4 rows (64 lanes x 16B = 1 KB = 4 x 256B rows).
    // lane -> row rloc = lane>>4 in group, chunk cc = lane&15; global chunk
    // swizzled: cc ^ (row & 15), row&15 = wv*4 + rloc (q*16 == 0 mod 16).
    const int rloc = lane >> 4, cc = lane & 15;
    const int r15 = wv * 4 + rloc;
    const bf16_t* bgbase = Wb + (size_t)r15 * V_ + ((cc ^ r15) * 8 - cc * 8);
    // note: HW writes lane at dest + lane*16; source per-lane offset handled
    // via the cc term folded below (bgsrc = row*V_ + (cc^r15)*8).
    const bf16_t* bgsrc = Wb + (size_t)r15 * V_ + (cc ^ r15) * 8;

    f32x4 acc[2][2];
#pragma unroll
    for (int i = 0; i < 2; ++i)
#pragma unroll
        for (int j = 0; j < 2; ++j) acc[i][j] = (f32x4){0.f, 0.f, 0.f, 0.f};

    // prologue: B DMA for k0=0 (8 instrs cover 128 rows), A regs for k0=0
#pragma unroll
    for (int q = 0; q < 8; ++q)
        gload_lds16(bgsrc + (size_t)q * 16 * V_, &Bs[(q * 16 + wv * 4) * BK]);
    float4 ap0 = *(const float4*)(aptr);
    float4 ap1 = *(const float4*)(aptr + 4);
    float4 ap2 = *(const float4*)(aptr + 64);
    float4 ap3 = *(const float4*)(aptr + 68);

    for (int k0 = 0; k0 < V_; k0 += BK) {
        bf16x8 av0, av1;
        av0[0] = (bf16_t)ap0.x; av0[1] = (bf16_t)ap0.y; av0[2] = (bf16_t)ap0.z; av0[3] = (bf16_t)ap0.w;
        av0[4] = (bf16_t)ap1.x; av0[5] = (bf16_t)ap1.y; av0[6] = (bf16_t)ap1.z; av0[7] = (bf16_t)ap1.w;
        av1[0] = (bf16_t)ap2.x; av1[1] = (bf16_t)ap2.y; av1[2] = (bf16_t)ap2.z; av1[3] = (bf16_t)ap2.w;
        av1[4] = (bf16_t)ap3.x; av1[5] = (bf16_t)ap3.y; av1[6] = (bf16_t)ap3.z; av1[7] = (bf16_t)ap3.w;
        *(bf16x8*)adst0 = av0;
        *(bf16x8*)adst1 = av1;
        __syncthreads();  // B DMA + A writes visible

        // kf-half 0 (kf = 0,1)
#pragma unroll
        for (int h = 0; h < 2; ++h) {
            bf16x8 af[2][2], bfr[2][2];
#pragma unroll
            for (int i = 0; i < 2; ++i)
#pragma unroll
                for (int kf = 0; kf < 2; ++kf)
                    af[i][kf] = *(bf16x8*)&As[(i * 16 + lm) * BK + ((((h * 2 + kf) * 4 + lq) ^ lm) * 8)];
#pragma unroll
            for (int j = 0; j < 2; ++j)
#pragma unroll
                for (int kf = 0; kf < 2; ++kf)
                    bfr[j][kf] = *(bf16x8*)&Bs[(n0w + j * 16 + lm) * BK + ((((h * 2 + kf) * 4 + lq) ^ lm) * 8)];
            if (h == 1 && k0 + BK < V_) {  // A reg prefetch for next iter
                ap0 = *(const float4*)(aptr + k0 + BK);
                ap1 = *(const float4*)(aptr + k0 + BK + 4);
                ap2 = *(const float4*)(aptr + k0 + BK + 64);
                ap3 = *(const float4*)(aptr + k0 + BK + 68);
            }
#pragma unroll
            for (int i = 0; i < 2; ++i)
#pragma unroll
                for (int j = 0; j < 2; ++j) {
                    acc[i][j] = __builtin_amdgcn_mfma_f32_16x16x32_bf16(af[i][0], bfr[j][0], acc[i][j], 0, 0, 0);
                    acc[i][j] = __builtin_amdgcn_mfma_f32_16x16x32_bf16(af[i][1], bfr[j][1], acc[i][j], 0, 0, 0);
                }
        }
        __syncthreads();  // done reading As/Bs
        if (k0 + BK < V_) {
#pragma unroll
            for (int q = 0; q < 8; ++q)
                gload_lds16(bgsrc + (size_t)q * 16 * V_ + (k0 + BK), &Bs[(q * 16 + wv * 4) * BK]);
        }
    }
    // epilogue: bias + relu. C/D: n = lane&15 (+16j), m = lq*4 + reg (+16i)
#pragma unroll
    for (int j = 0; j < 2; ++j) {
        const int n = n0w + j * 16 + lm;
        const float bi = (n < 64) ? U1b[n] : U2b[n - 64];
#pragma unroll
        for (int i = 0; i < 2; ++i)
#pragma unroll
            for (int r = 0; r < 4; ++r) {
                const int m = m0 + i * 16 + lq * 4 + r;
                LR[(size_t)m * 128 + n] = fmaxf(acc[i][j][r] + bi, 0.f);
            }
    }
}

// ---------------- kernel 3: fused d + Lbar + s (per batch) ----------------
__global__ __launch_bounds__(256) void kds(const float* __restrict__ LR, float* __restrict__ s) {
    __shared__ float dl[256];
    __shared__ float red[4][64];
    __shared__ float lbar[64];
    const int b = blockIdx.x, t = threadIdx.x;
    const float* Lb = LR + (size_t)b * N_ * 128;
    const float* row = Lb + (size_t)t * 128;
    float dd = 0.f;
#pragma unroll
    for (int k = 0; k < 64; k += 4) {
        float4 l = *(const float4*)(row + k);
        float4 r = *(const float4*)(row + 64 + k);
        dd += l.x * r.x + l.y * r.y + l.z * r.z + l.w * r.w;
    }
    const float dv = rsqrtf(dd + 1e-6f);
    dl[t] = dv;
    __syncthreads();
    const int k = t & 63, g = t >> 6;
    float acc = 0.f;
    for (int n = g; n < N_; n += 4)
        acc += dl[n] * Lb[(size_t)n * 128 + 64 + k];
    red[g][k] = acc;
    __syncthreads();
    if (t < 64) lbar[t] = red[0][t] + red[1][t] + red[2][t] + red[3][t];
    __syncthreads();
    float a2 = 0.f;
#pragma unroll 8
    for (int kk = 0; kk < 64; ++kk) a2 += lbar[kk] * row[kk];
    s[b * N_ + t] = ((float)(N_ + 1) - dv * a2) * (1.0f / (float)N_);
}

// ---------------- kernel 4: featsT[v][b] += partial over m-chunk ----------
__global__ __launch_bounds__(256) void kfeats(const float* __restrict__ Vmat,
                                              const float* __restrict__ s,
                                              float* __restrict__ featsT) {
    const int b = blockIdx.x >> 3, vc = (blockIdx.x >> 2) & 1, mc = blockIdx.x & 3;
    __shared__ float sl[64];
    const int t = threadIdx.x;
    if (t < 64) sl[t] = s[b * N_ + mc * 64 + t];
    __syncthreads();
    const int v = vc * 1024 + t * 4;
    const float* base = Vmat + (size_t)b * N_ * V_ + (size_t)mc * 64 * V_ + v;
    float4 a = {0.f, 0.f, 0.f, 0.f};
    for (int m = 0; m < 64; m += 8) {
        float4 x[8];
#pragma unroll
        for (int u = 0; u < 8; ++u) x[u] = *(const float4*)(base + (size_t)(m + u) * V_);
#pragma unroll
        for (int u = 0; u < 8; ++u) {
            float sv = sl[m + u];
            a.x += sv * x[u].x; a.y += sv * x[u].y;
            a.z += sv * x[u].z; a.w += sv * x[u].w;
        }
    }
    atomicAdd(&featsT[(size_t)(v + 0) * 64 + b], a.x);
    atomicAdd(&featsT[(size_t)(v + 1) * 64 + b], a.y);
    atomicAdd(&featsT[(size_t)(v + 2) * 64 + b], a.z);
    atomicAdd(&featsT[(size_t)(v + 3) * 64 + b], a.w);
}

// ---------------- kernel 5: fused linear + BatchNorm (512 thr, 8-way K) ---
// (b_lin dropped: constant per-column shift cancels in BatchNorm)
__global__ __launch_bounds__(512) void klinbn(const float* __restrict__ featsT,
                                              const float* __restrict__ Wl,
                                              const float* __restrict__ gamma,
                                              const float* __restrict__ beta,
                                              float* __restrict__ out) {
    __shared__ float red[8][4][64];
    const int e0 = blockIdx.x * 4;
    const int t = threadIdx.x, b = t & 63, g = t >> 6;  // g: 0..7 k-slices
    const float* w0 = Wl + (size_t)(e0 + 0) * V_ + g * 256;
    const float* w1 = Wl + (size_t)(e0 + 1) * V_ + g * 256;
    const float* w2 = Wl + (size_t)(e0 + 2) * V_ + g * 256;
    const float* w3 = Wl + (size_t)(e0 + 3) * V_ + g * 256;
    const float* f = featsT + (size_t)g * 256 * 64 + b;
    float a0 = 0.f, a1 = 0.f, a2 = 0.f, a3 = 0.f;
#pragma unroll 4
    for (int k = 0; k < 256; ++k) {
        float fv = f[(size_t)k * 64];
        a0 += fv * w0[k]; a1 += fv * w1[k]; a2 += fv * w2[k]; a3 += fv * w3[k];
    }
    red[g][0][b] = a0; red[g][1][b] = a1; red[g][2][b] = a2; red[g][3][b] = a3;
    __syncthreads();
    if (t < 256) {
        const int e = t >> 6;  // wave e owns e-row e0+e across lanes b
        float v = 0.f;
#pragma unroll
        for (int gg = 0; gg < 8; ++gg) v += red[gg][e][b];
        float sum = v;
#pragma unroll
        for (int o = 1; o < 64; o <<= 1) sum += __shfl_xor(sum, o, 64);
        float mu = sum * (1.f / 64.f);
        float dvv = v - mu;
        float q = dvv * dvv;
#pragma unroll
        for (int o = 1; o < 64; o <<= 1) q += __shfl_xor(q, o, 64);
        float inv = rsqrtf(q * (1.f / 64.f) + 1e-5f);
        red[0][e][b] = gamma[e0 + e] * dvv * inv + beta[e0 + e];
    }
    __syncthreads();
    if (t < 256) {
        const int b2 = t >> 2, j = t & 3;
        out[(size_t)b2 * E_ + e0 + j] = red[0][j][b2];
    }
}

extern "C" void kernel_launch(void* const* d_in, const int* in_sizes, int n_in,
                              void* d_out, int out_size, void* d_ws, size_t ws_size,
                              hipStream_t stream) {
    const float* Vmat = (const float*)d_in[0];
    const float* U1v  = (const float*)d_in[1];
    const float* U1g  = (const float*)d_in[2];
    const float* U1b  = (const float*)d_in[3];
    const float* U2v  = (const float*)d_in[4];
    const float* U2g  = (const float*)d_in[5];
    const float* U2b  = (const float*)d_in[6];
    const float* Wl   = (const float*)d_in[7];
    // d_in[8] = b_lin: unused (cancels in BatchNorm)
    const float* gam  = (const float*)d_in[9];
    const float* bet  = (const float*)d_in[10];

    float*  ws     = (float*)d_ws;
    float*  s      = ws + OFF_S;
    float*  LR     = ws + OFF_LR;
    float*  featsT = ws + OFF_FT;
    bf16_t* Wb     = (bf16_t*)(ws + OFF_WB);

    kprep  <<<128, 256, 0, stream>>>(U1v, U1g, U2v, U2g, Wb, featsT);
    gemm_lr<<<MROWS / 32, 256, 0, stream>>>(Vmat, Wb, U1b, U2b, LR);
    kds    <<<B_, 256, 0, stream>>>(LR, s);
    kfeats <<<B_ * 8, 256, 0, stream>>>(Vmat, s, featsT);
    klinbn <<<E_ / 4, 512, 0, stream>>>(featsT, Wl, gam, bet, (float*)d_out);
}

// Round 10
// 288.985 us; speedup vs baseline: 1.3728x; 1.0396x over previous
//
#include <hip/hip_runtime.h>

#define B_ 64
#define N_ 256
#define V_ 2048
#define E_ 1024
#define MROWS 16384  // B_*N_

typedef __bf16 bf16_t;
typedef bf16_t bf16x8 __attribute__((ext_vector_type(8)));
typedef float f32x4 __attribute__((ext_vector_type(4)));

// ws layout (float units):
#define OFF_S   0         // s      [16384]
#define OFF_LR  16384     // LR     [16384*128]
#define OFF_FT  2113536   // ftp: 4 partial buffers x [2048*64]
#define FTSZ    131072
#define OFF_WB  2637824   // Wb bf16[128*2048] (= 131072 floats)

__device__ __forceinline__ void gload_lds16(const bf16_t* g, bf16_t* l) {
    __builtin_amdgcn_global_load_lds((const __attribute__((address_space(1))) void*)g,
                                     (__attribute__((address_space(3))) void*)l, 16, 0, 0);
}

// ---------------- kernel 1: weight-norm scale folded into bf16 weights ----
__global__ void kprep(const float* __restrict__ U1v, const float* __restrict__ U1g,
                      const float* __restrict__ U2v, const float* __restrict__ U2g,
                      bf16_t* __restrict__ Wb) {
    __shared__ float red[256];
    __shared__ float sc;
    const int r = blockIdx.x;  // 0..127
    const float* v = (r < 64) ? (U1v + (size_t)r * V_) : (U2v + (size_t)(r - 64) * V_);
    float ss = 0.f;
    for (int i = threadIdx.x; i < V_; i += 256) { float x = v[i]; ss += x * x; }
    red[threadIdx.x] = ss;
    __syncthreads();
    for (int o = 128; o > 0; o >>= 1) {
        if (threadIdx.x < (unsigned)o) red[threadIdx.x] += red[threadIdx.x + o];
        __syncthreads();
    }
    if (threadIdx.x == 0) {
        float g = (r < 64) ? U1g[r] : U2g[r - 64];
        sc = g * rsqrtf(red[0]);
    }
    __syncthreads();
    const float s = sc;
    const int k = threadIdx.x * 8;
    float4 f0 = *(const float4*)(v + k);
    float4 f1 = *(const float4*)(v + k + 4);
    bf16x8 o;
    o[0] = (bf16_t)(f0.x * s); o[1] = (bf16_t)(f0.y * s);
    o[2] = (bf16_t)(f0.z * s); o[3] = (bf16_t)(f0.w * s);
    o[4] = (bf16_t)(f1.x * s); o[5] = (bf16_t)(f1.y * s);
    o[6] = (bf16_t)(f1.z * s); o[7] = (bf16_t)(f1.w * s);
    *(bf16x8*)(Wb + (size_t)r * V_ + k) = o;
}

// ---------------- kernel 2: MFMA bf16 projections, BK=128 ------------------
// LR[16384x128] = relu(Vmat * Wb^T + bias). Tile 32m x 128n, grid 512.
// B via global_load_lds dwordx4 (dist 1), A fp32 reg-prefetch + in-reg bf16
// convert, XOR-swizzled LDS (mod 16), 2 barriers per 128-K iter (16 iters).
// NOTE: dbuf/no-barrier/split-K/dist-2 all regress (R4-R7) — do not retry.
#define BK 128
__global__ __launch_bounds__(256) void gemm_lr(
    const float* __restrict__ V, const bf16_t* __restrict__ Wb,
    const float* __restrict__ U1b, const float* __restrict__ U2b,
    float* __restrict__ LR) {
    __shared__ bf16_t As[32 * BK];    // 8 KB
    __shared__ bf16_t Bs[128 * BK];   // 32 KB
    const int t = threadIdx.x;
    const int m0 = blockIdx.x * 32;
    const int wv = t >> 6, lane = t & 63;
    const int lm = lane & 15, lq = lane >> 4;
    const int n0w = wv * 32;

    // A staging: thread -> (row ar 0..31, chunks au and au+8 of 16), XOR mod16
    const int ar = t >> 3, au = t & 7;
    const float* aptr = V + (size_t)(m0 + ar) * V_ + au * 8;
    bf16_t* adst0 = &As[ar * BK + ((au ^ (ar & 15)) * 8)];
    bf16_t* adst1 = &As[ar * BK + (((au + 8) ^ (ar & 15)) * 8)];

    // B DMA: instr covers 4 rows (64 lanes x 16B = 1KB); lane -> row
    // r15 = wv*4 + (lane>>4), chunk cc = lane&15, global-side XOR swizzle.
    const int rloc = lane >> 4, cc = lane & 15;
    const int r15 = wv * 4 + rloc;
    const bf16_t* bgsrc = Wb + (size_t)r15 * V_ + (cc ^ r15) * 8;

    f32x4 acc[2][2];
#pragma unroll
    for (int i = 0; i < 2; ++i)
#pragma unroll
        for (int j = 0; j < 2; ++j) acc[i][j] = (f32x4){0.f, 0.f, 0.f, 0.f};

    // prologue: B DMA for k0=0 (8 instrs cover 128 rows), A regs for k0=0
#pragma unroll
    for (int q = 0; q < 8; ++q)
        gload_lds16(bgsrc + (size_t)q * 16 * V_, &Bs[(q * 16 + wv * 4) * BK]);
    float4 ap0 = *(const float4*)(aptr);
    float4 ap1 = *(const float4*)(aptr + 4);
    float4 ap2 = *(const float4*)(aptr + 64);
    float4 ap3 = *(const float4*)(aptr + 68);

    for (int k0 = 0; k0 < V_; k0 += BK) {
        bf16x8 av0, av1;
        av0[0] = (bf16_t)ap0.x; av0[1] = (bf16_t)ap0.y; av0[2] = (bf16_t)ap0.z; av0[3] = (bf16_t)ap0.w;
        av0[4] = (bf16_t)ap1.x; av0[5] = (bf16_t)ap1.y; av0[6] = (bf16_t)ap1.z; av0[7] = (bf16_t)ap1.w;
        av1[0] = (bf16_t)ap2.x; av1[1] = (bf16_t)ap2.y; av1[2] = (bf16_t)ap2.z; av1[3] = (bf16_t)ap2.w;
        av1[4] = (bf16_t)ap3.x; av1[5] = (bf16_t)ap3.y; av1[6] = (bf16_t)ap3.z; av1[7] = (bf16_t)ap3.w;
        *(bf16x8*)adst0 = av0;
        *(bf16x8*)adst1 = av1;
        __syncthreads();  // B DMA + A writes visible

#pragma unroll
        for (int h = 0; h < 2; ++h) {
            bf16x8 af[2][2], bfr[2][2];
#pragma unroll
            for (int i = 0; i < 2; ++i)
#pragma unroll
                for (int kf = 0; kf < 2; ++kf)
                    af[i][kf] = *(bf16x8*)&As[(i * 16 + lm) * BK + ((((h * 2 + kf) * 4 + lq) ^ lm) * 8)];
#pragma unroll
            for (int j = 0; j < 2; ++j)
#pragma unroll
                for (int kf = 0; kf < 2; ++kf)
                    bfr[j][kf] = *(bf16x8*)&Bs[(n0w + j * 16 + lm) * BK + ((((h * 2 + kf) * 4 + lq) ^ lm) * 8)];
            if (h == 1 && k0 + BK < V_) {  // A reg prefetch for next iter
                ap0 = *(const float4*)(aptr + k0 + BK);
                ap1 = *(const float4*)(aptr + k0 + BK + 4);
                ap2 = *(const float4*)(aptr + k0 + BK + 64);
                ap3 = *(const float4*)(aptr + k0 + BK + 68);
            }
#pragma unroll
            for (int i = 0; i < 2; ++i)
#pragma unroll
                for (int j = 0; j < 2; ++j) {
                    acc[i][j] = __builtin_amdgcn_mfma_f32_16x16x32_bf16(af[i][0], bfr[j][0], acc[i][j], 0, 0, 0);
                    acc[i][j] = __builtin_amdgcn_mfma_f32_16x16x32_bf16(af[i][1], bfr[j][1], acc[i][j], 0, 0, 0);
                }
        }
        __syncthreads();  // done reading As/Bs
        if (k0 + BK < V_) {
#pragma unroll
            for (int q = 0; q < 8; ++q)
                gload_lds16(bgsrc + (size_t)q * 16 * V_ + (k0 + BK), &Bs[(q * 16 + wv * 4) * BK]);
        }
    }
    // epilogue: bias + relu. C/D: n = lane&15 (+16j), m = lq*4 + reg (+16i)
#pragma unroll
    for (int j = 0; j < 2; ++j) {
        const int n = n0w + j * 16 + lm;
        const float bi = (n < 64) ? U1b[n] : U2b[n - 64];
#pragma unroll
        for (int i = 0; i < 2; ++i)
#pragma unroll
            for (int r = 0; r < 4; ++r) {
                const int m = m0 + i * 16 + lq * 4 + r;
                LR[(size_t)m * 128 + n] = fmaxf(acc[i][j][r] + bi, 0.f);
            }
    }
}

// ---------------- kernel 3: fused d + Lbar + s (per batch) ----------------
__global__ __launch_bounds__(256) void kds(const float* __restrict__ LR, float* __restrict__ s) {
    __shared__ float dl[256];
    __shared__ float red[4][64];
    __shared__ float lbar[64];
    const int b = blockIdx.x, t = threadIdx.x;
    const float* Lb = LR + (size_t)b * N_ * 128;
    const float* row = Lb + (size_t)t * 128;
    float dd = 0.f;
#pragma unroll
    for (int k = 0; k < 64; k += 4) {
        float4 l = *(const float4*)(row + k);
        float4 r = *(const float4*)(row + 64 + k);
        dd += l.x * r.x + l.y * r.y + l.z * r.z + l.w * r.w;
    }
    const float dv = rsqrtf(dd + 1e-6f);
    dl[t] = dv;
    __syncthreads();
    const int k = t & 63, g = t >> 6;
    float acc = 0.f;
    for (int n = g; n < N_; n += 4)
        acc += dl[n] * Lb[(size_t)n * 128 + 64 + k];
    red[g][k] = acc;
    __syncthreads();
    if (t < 64) lbar[t] = red[0][t] + red[1][t] + red[2][t] + red[3][t];
    __syncthreads();
    float a2 = 0.f;
#pragma unroll 8
    for (int kk = 0; kk < 64; ++kk) a2 += lbar[kk] * row[kk];
    s[b * N_ + t] = ((float)(N_ + 1) - dv * a2) * (1.0f / (float)N_);
}

// ---------------- kernel 4: kfeats partials, NO atomics -------------------
// grid 512: b(6b) x vc(1b) x mc(2b). Each block writes its m-chunk partial
// to ftp[mc] (disjoint buffers, plain stores); klinbn sums the 4 partials.
__global__ __launch_bounds__(256) void kfeats(const float* __restrict__ Vmat,
                                              const float* __restrict__ s,
                                              float* __restrict__ ftp) {
    const int b = blockIdx.x >> 3, vc = (blockIdx.x >> 2) & 1, mc = blockIdx.x & 3;
    __shared__ float sl[64];
    const int t = threadIdx.x;
    if (t < 64) sl[t] = s[b * N_ + mc * 64 + t];
    __syncthreads();
    const int v = vc * 1024 + t * 4;
    const float* base = Vmat + (size_t)b * N_ * V_ + (size_t)mc * 64 * V_ + v;
    float4 a = {0.f, 0.f, 0.f, 0.f};
    for (int m = 0; m < 64; m += 16) {
        float4 x[16];
#pragma unroll
        for (int u = 0; u < 16; ++u) x[u] = *(const float4*)(base + (size_t)(m + u) * V_);
#pragma unroll
        for (int u = 0; u < 16; ++u) {
            float sv = sl[m + u];
            a.x += sv * x[u].x; a.y += sv * x[u].y;
            a.z += sv * x[u].z; a.w += sv * x[u].w;
        }
    }
    float* dst = ftp + (size_t)mc * FTSZ;
    dst[(size_t)(v + 0) * 64 + b] = a.x;
    dst[(size_t)(v + 1) * 64 + b] = a.y;
    dst[(size_t)(v + 2) * 64 + b] = a.z;
    dst[(size_t)(v + 3) * 64 + b] = a.w;
}

// ---------------- kernel 5: fused linear + BatchNorm (512 thr, 8-way K) ---
// sums the 4 kfeats partials inline. (b_lin dropped: cancels in BatchNorm)
__global__ __launch_bounds__(512) void klinbn(const float* __restrict__ ftp,
                                              const float* __restrict__ Wl,
                                              const float* __restrict__ gamma,
                                              const float* __restrict__ beta,
                                              float* __restrict__ out) {
    __shared__ float red[8][4][64];
    const int e0 = blockIdx.x * 4;
    const int t = threadIdx.x, b = t & 63, g = t >> 6;  // g: 0..7 k-slices
    const float* w0 = Wl + (size_t)(e0 + 0) * V_ + g * 256;
    const float* w1 = Wl + (size_t)(e0 + 1) * V_ + g * 256;
    const float* w2 = Wl + (size_t)(e0 + 2) * V_ + g * 256;
    const float* w3 = Wl + (size_t)(e0 + 3) * V_ + g * 256;
    const float* f0 = ftp + 0 * FTSZ + (size_t)g * 256 * 64 + b;
    const float* f1 = ftp + 1 * FTSZ + (size_t)g * 256 * 64 + b;
    const float* f2 = ftp + 2 * FTSZ + (size_t)g * 256 * 64 + b;
    const float* f3 = ftp + 3 * FTSZ + (size_t)g * 256 * 64 + b;
    float a0 = 0.f, a1 = 0.f, a2 = 0.f, a3 = 0.f;
#pragma unroll 4
    for (int k = 0; k < 256; ++k) {
        const size_t o = (size_t)k * 64;
        float fv = (f0[o] + f1[o]) + (f2[o] + f3[o]);
        a0 += fv * w0[k]; a1 += fv * w1[k]; a2 += fv * w2[k]; a3 += fv * w3[k];
    }
    red[g][0][b] = a0; red[g][1][b] = a1; red[g][2][b] = a2; red[g][3][b] = a3;
    __syncthreads();
    if (t < 256) {
        const int e = t >> 6;  // wave e owns e-row e0+e across lanes b
        float v = 0.f;
#pragma unroll
        for (int gg = 0; gg < 8; ++gg) v += red[gg][e][b];
        float sum = v;
#pragma unroll
        for (int o = 1; o < 64; o <<= 1) sum += __shfl_xor(sum, o, 64);
        float mu = sum * (1.f / 64.f);
        float dvv = v - mu;
        float q = dvv * dvv;
#pragma unroll
        for (int o = 1; o < 64; o <<= 1) q += __shfl_xor(q, o, 64);
        float inv = rsqrtf(q * (1.f / 64.f) + 1e-5f);
        red[0][e][b] = gamma[e0 + e] * dvv * inv + beta[e0 + e];
    }
    __syncthreads();
    if (t < 256) {
        const int b2 = t >> 2, j = t & 3;
        out[(size_t)b2 * E_ + e0 + j] = red[0][j][b2];
    }
}

extern "C" void kernel_launch(void* const* d_in, const int* in_sizes, int n_in,
                              void* d_out, int out_size, void* d_ws, size_t ws_size,
                              hipStream_t stream) {
    const float* Vmat = (const float*)d_in[0];
    const float* U1v  = (const float*)d_in[1];
    const float* U1g  = (const float*)d_in[2];
    const float* U1b  = (const float*)d_in[3];
    const float* U2v  = (const float*)d_in[4];
    const float* U2g  = (const float*)d_in[5];
    const float* U2b  = (const float*)d_in[6];
    const float* Wl   = (const float*)d_in[7];
    // d_in[8] = b_lin: unused (cancels in BatchNorm)
    const float* gam  = (const float*)d_in[9];
    const float* bet  = (const float*)d_in[10];

    float*  ws     = (float*)d_ws;
    float*  s      = ws + OFF_S;
    float*  LR     = ws + OFF_LR;
    float*  ftp    = ws + OFF_FT;
    bf16_t* Wb     = (bf16_t*)(ws + OFF_WB);

    kprep  <<<128, 256, 0, stream>>>(U1v, U1g, U2v, U2g, Wb);
    gemm_lr<<<MROWS / 32, 256, 0, stream>>>(Vmat, Wb, U1b, U2b, LR);
    kds    <<<B_, 256, 0, stream>>>(LR, s);
    kfeats <<<B_ * 8, 256, 0, stream>>>(Vmat, s, ftp);
    klinbn <<<E_ / 4, 512, 0, stream>>>(ftp, Wl, gam, bet, (float*)d_out);
}